// Round 2
// baseline (28169.507 us; speedup 1.0000x reference)
//
#include <hip/hip_runtime.h>

// ---------------------------------------------------------------------------
// FocusModel: embed -> bidir LSTM (E=512->HE=512) -> bidir LSTM (1024->512)
//          -> decoder LSTM (HD=1024, one-hot argmax feedback) -> softmax/loss
// R5: R4's hipLaunchCooperativeKernel never executed in this harness (all
// outputs stayed zero; prob passed only via threshold floor, loss failed at
// exactly the reference value). Same persistent-kernel structure, but with
// regular <<<>>> launches + a hand-rolled device-scope grid barrier:
//   - 128 blocks x 64 threads (1 wave/block) -> always co-resident on 256 CUs
//   - arrive: agent-scope atomic fetch_add; last arrival resets count and
//     bumps a generation counter (RELEASE); waiters spin on ACQUIRE loads.
//   - __threadfence() before/after handles cross-XCD L2 writeback/invalidate.
// Math is identical to the R3-verified per-step kernels.
// ---------------------------------------------------------------------------

typedef __bf16 bf16_t;
typedef __bf16 bf16x8 __attribute__((ext_vector_type(8)));
typedef __bf16 bf16x4 __attribute__((ext_vector_type(4)));
typedef float  f32x4  __attribute__((ext_vector_type(4)));

#define NB 128
#define LQ 160
#define EE 512
#define HE 512
#define HD 1024
#define TT 128

__device__ __forceinline__ f32x4 mfma16(bf16x8 a, bf16x8 b, f32x4 c) {
    return __builtin_amdgcn_mfma_f32_16x16x32_bf16(a, b, c, 0, 0, 0);
}
__device__ __forceinline__ bf16x8 ldf(const bf16_t* p) { return *(const bf16x8*)p; }
__device__ __forceinline__ float sigf(float x) { return 1.0f / (1.0f + __expf(-x)); }

// Device-scope grid barrier (persistent-kernel sync). nblk blocks, 1 wave each.
// g holds the generation observed at kernel entry + barriers passed so far.
__device__ __forceinline__ void gsync(unsigned* cnt, unsigned* gen,
                                      unsigned nblk, unsigned& g) {
    __threadfence();   // release: write back this wave's stores (cross-XCD)
    __syncthreads();
    if (threadIdx.x == 0) {
        unsigned old = __hip_atomic_fetch_add(cnt, 1u, __ATOMIC_ACQ_REL,
                                              __HIP_MEMORY_SCOPE_AGENT);
        if (old == nblk - 1u) {
            __hip_atomic_store(cnt, 0u, __ATOMIC_RELAXED, __HIP_MEMORY_SCOPE_AGENT);
            __hip_atomic_fetch_add(gen, 1u, __ATOMIC_RELEASE, __HIP_MEMORY_SCOPE_AGENT);
        } else {
            while (__hip_atomic_load(gen, __ATOMIC_ACQUIRE,
                                     __HIP_MEMORY_SCOPE_AGENT) <= g) {
                __builtin_amdgcn_s_sleep(1);
            }
        }
    }
    __syncthreads();
    __threadfence();   // acquire: invalidate stale L1/L2 before new reads
    g += 1;
}

// f32 -> bf16 bulk convert (n4 = n/4, all sizes divisible by 4).
__global__ __launch_bounds__(256) void k_cvt(const float* __restrict__ src,
                                             bf16_t* __restrict__ dst, int n4) {
    int i = blockIdx.x * 256 + threadIdx.x;
    if (i < n4) {
        float4 v = ((const float4*)src)[i];
        bf16x4 o;
        o[0] = (bf16_t)v.x; o[1] = (bf16_t)v.y; o[2] = (bf16_t)v.z; o[3] = (bf16_t)v.w;
        ((bf16x4*)dst)[i] = o;
    }
}

// ---------------------------------------------------------------------------
// Chunked input projection, layer 0. Rows m = (s-s0)*128 + b; per-direction
// source timestep t = d ? L-1-s : s; A-row = embedB[ids[b][t]] (gather fused).
// grid (CH*2, 32, 2), block 64 (wave per 64x64 tile, K=512).
// ---------------------------------------------------------------------------
__global__ __launch_bounds__(64) void k_xg0c(const int* __restrict__ ids,
                                             const bf16_t* __restrict__ embed,
                                             const bf16_t* __restrict__ wih,
                                             bf16_t* __restrict__ xgc,
                                             int s0) {
    const int lane = threadIdx.x;
    const int l15 = lane & 15, quad = lane >> 4;
    const int m0 = blockIdx.x * 64;
    const int n0 = blockIdx.y * 64;
    const int d  = blockIdx.z;
    const bf16_t* Wd = wih + (size_t)d * 2048 * 512;

    const bf16_t* arow[4];
#pragma unroll
    for (int mi = 0; mi < 4; ++mi) {
        int m = m0 + mi * 16 + l15;
        int b = m & 127, s = s0 + (m >> 7);
        int t = d ? (LQ - 1 - s) : s;
        int id = ids[b * LQ + t];
        arow[mi] = embed + (size_t)id * EE;
    }
    const bf16_t* brow[4];
#pragma unroll
    for (int ni = 0; ni < 4; ++ni) brow[ni] = Wd + (size_t)(n0 + ni * 16 + l15) * 512;

    f32x4 acc[4][4] = {};
    for (int kb = 0; kb < 512; kb += 32) {
        bf16x8 af[4], bfr[4];
#pragma unroll
        for (int mi = 0; mi < 4; ++mi) af[mi] = ldf(arow[mi] + kb + quad * 8);
#pragma unroll
        for (int ni = 0; ni < 4; ++ni) bfr[ni] = ldf(brow[ni] + kb + quad * 8);
#pragma unroll
        for (int mi = 0; mi < 4; ++mi)
#pragma unroll
            for (int ni = 0; ni < 4; ++ni)
                acc[mi][ni] = mfma16(af[mi], bfr[ni], acc[mi][ni]);
    }
#pragma unroll
    for (int mi = 0; mi < 4; ++mi)
#pragma unroll
        for (int ni = 0; ni < 4; ++ni)
#pragma unroll
            for (int r = 0; r < 4; ++r) {
                int m = m0 + mi * 16 + quad * 4 + r;
                int n = n0 + ni * 16 + l15;
                xgc[(size_t)m * 4096 + d * 2048 + n] = (bf16_t)acc[mi][ni][r];
            }
}

// Chunked input projection, layer 1: A-row = h1[t*128+b] (1024 wide), K=1024.
__global__ __launch_bounds__(64) void k_xg1c(const bf16_t* __restrict__ h1,
                                             const bf16_t* __restrict__ wih,
                                             bf16_t* __restrict__ xgc,
                                             int s0) {
    const int lane = threadIdx.x;
    const int l15 = lane & 15, quad = lane >> 4;
    const int m0 = blockIdx.x * 64;
    const int n0 = blockIdx.y * 64;
    const int d  = blockIdx.z;
    const bf16_t* Wd = wih + (size_t)d * 2048 * 1024;

    const bf16_t* arow[4];
#pragma unroll
    for (int mi = 0; mi < 4; ++mi) {
        int m = m0 + mi * 16 + l15;
        int b = m & 127, s = s0 + (m >> 7);
        int t = d ? (LQ - 1 - s) : s;
        arow[mi] = h1 + ((size_t)t * NB + b) * 1024;
    }
    const bf16_t* brow[4];
#pragma unroll
    for (int ni = 0; ni < 4; ++ni) brow[ni] = Wd + (size_t)(n0 + ni * 16 + l15) * 1024;

    f32x4 acc[4][4] = {};
    for (int kb = 0; kb < 1024; kb += 32) {
        bf16x8 af[4], bfr[4];
#pragma unroll
        for (int mi = 0; mi < 4; ++mi) af[mi] = ldf(arow[mi] + kb + quad * 8);
#pragma unroll
        for (int ni = 0; ni < 4; ++ni) bfr[ni] = ldf(brow[ni] + kb + quad * 8);
#pragma unroll
        for (int mi = 0; mi < 4; ++mi)
#pragma unroll
            for (int ni = 0; ni < 4; ++ni)
                acc[mi][ni] = mfma16(af[mi], bfr[ni], acc[mi][ni]);
    }
#pragma unroll
    for (int mi = 0; mi < 4; ++mi)
#pragma unroll
        for (int ni = 0; ni < 4; ++ni)
#pragma unroll
            for (int r = 0; r < 4; ++r) {
                int m = m0 + mi * 16 + quad * 4 + r;
                int n = n0 + ni * 16 + l15;
                xgc[(size_t)m * 4096 + d * 2048 + n] = (bf16_t)acc[mi][ni][r];
            }
}

// ---------------------------------------------------------------------------
// Persistent encoder chunk: CH recurrent steps with gsync between steps.
// 128 blocks x 64 threads; block bi -> m-block (bi&1), col-block ((bi>>1)&31),
// dir (bi>>6). Same wave tile as the old k_enc_step: 64 batch x 4 gates x 16.
// ---------------------------------------------------------------------------
__global__ __launch_bounds__(64) void k_enc_chunk(bf16_t* __restrict__ hst,
                                                  const bf16_t* __restrict__ whh,
                                                  const float* __restrict__ bias,
                                                  const bf16_t* __restrict__ xgc,
                                                  float* __restrict__ cst,
                                                  bf16_t* __restrict__ hlay,
                                                  unsigned* __restrict__ bcnt,
                                                  unsigned* __restrict__ bgen,
                                                  int s0, int nsteps) {
    unsigned g = __hip_atomic_load(bgen, __ATOMIC_ACQUIRE, __HIP_MEMORY_SCOPE_AGENT);
    const int lane = threadIdx.x;
    const int l15 = lane & 15, quad = lane >> 4;
    const int bi = blockIdx.x;
    const int m0 = (bi & 1) * 64;
    const int c0 = ((bi >> 1) & 31) * 16;
    const int d  = bi >> 6;
    const size_t HSB = (size_t)2 * NB * 512;  // elems per double-buffer half

    const bf16_t* Wd = whh + (size_t)d * 2048 * 512;
    const bf16_t* brow[4];
#pragma unroll
    for (int gg2 = 0; gg2 < 4; ++gg2) brow[gg2] = Wd + (size_t)(gg2 * 512 + c0 + l15) * 512;
    const int c = c0 + l15;
    float bv[4];
#pragma unroll
    for (int gg2 = 0; gg2 < 4; ++gg2) bv[gg2] = bias[d * 2048 + gg2 * 512 + c];
    size_t aoff[4];
#pragma unroll
    for (int mi = 0; mi < 4; ++mi) aoff[mi] = (size_t)(m0 + mi * 16 + l15) * 512;

    for (int s = s0; s < s0 + nsteps; ++s) {
        const int t = d ? (LQ - 1 - s) : s;
        const bf16_t* hd = hst + (size_t)(s & 1) * HSB + (size_t)d * (NB * HE);
        bf16_t* houtb    = hst + (size_t)((s + 1) & 1) * HSB;

        f32x4 acc[4][4] = {};  // [mi][gate]
        for (int kb = 0; kb < 512; kb += 32) {
            bf16x8 af[4], bfr[4];
#pragma unroll
            for (int mi = 0; mi < 4; ++mi) af[mi] = ldf(hd + aoff[mi] + kb + quad * 8);
#pragma unroll
            for (int gg2 = 0; gg2 < 4; ++gg2) bfr[gg2] = ldf(brow[gg2] + kb + quad * 8);
#pragma unroll
            for (int mi = 0; mi < 4; ++mi)
#pragma unroll
                for (int gg2 = 0; gg2 < 4; ++gg2)
                    acc[mi][gg2] = mfma16(af[mi], bfr[gg2], acc[mi][gg2]);
        }

#pragma unroll
        for (int mi = 0; mi < 4; ++mi)
#pragma unroll
            for (int r = 0; r < 4; ++r) {
                int m = m0 + mi * 16 + quad * 4 + r;
                size_t xoff = ((size_t)(s - s0) * NB + m) * 4096 + (size_t)d * 2048;
                float gi = acc[mi][0][r] + (float)xgc[xoff + 0 * 512 + c] + bv[0];
                float gf = acc[mi][1][r] + (float)xgc[xoff + 1 * 512 + c] + bv[1];
                float gg = acc[mi][2][r] + (float)xgc[xoff + 2 * 512 + c] + bv[2];
                float go = acc[mi][3][r] + (float)xgc[xoff + 3 * 512 + c] + bv[3];
                size_t coff = ((size_t)d * NB + m) * 512 + c;
                float cn = sigf(gf) * cst[coff] + sigf(gi) * tanhf(gg);
                float hn = sigf(go) * tanhf(cn);
                cst[coff] = cn;
                houtb[coff] = (bf16_t)hn;
                hlay[((size_t)t * NB + m) * 1024 + (size_t)d * 512 + c] = (bf16_t)hn;
            }
        if (s + 1 < s0 + nsteps) gsync(bcnt, bgen, 128, g);
    }
}

// ---------------------------------------------------------------------------
// Persistent decoder: init + 160 steps in one launch (128 blocks x 64 thr).
// Per step: phase A (gate GEMM + cell, block bi -> m0=(bi&1)*64, c0=(bi>>1)*16)
// -> gsync -> phase B (block bi = batch b; lane n computes tags n and n+64,
// shuffle softmax / first-max argmax; loss in-register) -> gsync.
// One atomicAdd per block at the end writes the loss scalar.
// ---------------------------------------------------------------------------
__global__ __launch_bounds__(64) void k_dec_persist(const bf16_t* __restrict__ encb,
                                                    const bf16_t* __restrict__ whh,
                                                    const float* __restrict__ bias,
                                                    const float* __restrict__ wih,
                                                    const float* __restrict__ out_w,
                                                    const float* __restrict__ out_b,
                                                    const int* __restrict__ tags,
                                                    bf16_t* __restrict__ hbuf,
                                                    float* __restrict__ cst,
                                                    float* __restrict__ hdec,
                                                    int* __restrict__ idx,
                                                    unsigned* __restrict__ bcnt,
                                                    unsigned* __restrict__ bgen,
                                                    float* __restrict__ prob_out,
                                                    float* __restrict__ loss_out) {
    unsigned g = __hip_atomic_load(bgen, __ATOMIC_ACQUIRE, __HIP_MEMORY_SCOPE_AGENT);
    const int lane = threadIdx.x;
    const int bi = blockIdx.x;
    const int l15 = lane & 15, quad = lane >> 4;
    const int m0 = (bi & 1) * 64;
    const int c0 = (bi >> 1) * 16;

    // ---- init: hbuf[buf0] = enc[0] (h0=0 + enc_0), c0 = [fb, fb] ----
    for (int i = bi * 64 + lane; i < NB * HD; i += 128 * 64) {
        int b2 = i >> 10, k = i & 1023;
        hbuf[i] = encb[i];
        cst[i] = (float)encb[((size_t)b2 << 10) + 512 + (k & 511)];
    }
    if (bi < 2) idx[bi * 64 + lane] = -1;

    // ---- hoisted gate-phase constants ----
    const bf16_t* brow[4];
#pragma unroll
    for (int gg = 0; gg < 4; ++gg) brow[gg] = whh + (size_t)(gg * 1024 + c0 + l15) * 1024;
    const int c = c0 + l15;
    float bv[4];
#pragma unroll
    for (int gg = 0; gg < 4; ++gg) bv[gg] = bias[gg * 1024 + c];
    size_t aoff[4];
#pragma unroll
    for (int mi = 0; mi < 4; ++mi) aoff[mi] = (size_t)(m0 + mi * 16 + l15) * 1024;

    // ---- hoisted logits constants (block bi = batch) ----
    const int b = bi;
    const float4* wl0 = (const float4*)(out_w + (size_t)lane * HD);
    const float4* wl1 = (const float4*)(out_w + (size_t)(lane + 64) * HD);
    const float ob0 = out_b[lane], ob1 = out_b[lane + 64];
    float loss_acc = 0.0f;

    gsync(bcnt, bgen, 128, g);

    for (int t = 0; t < LQ; ++t) {
        // ================= phase A: gates + cell =================
        const bf16_t* hin = hbuf + (size_t)(t & 1) * (NB * HD);
        bf16_t* hout      = hbuf + (size_t)((t + 1) & 1) * (NB * HD);

        f32x4 acc[4][4] = {};
        for (int kb = 0; kb < 1024; kb += 32) {
            bf16x8 af[4], bfr[4];
#pragma unroll
            for (int mi = 0; mi < 4; ++mi) af[mi] = ldf(hin + aoff[mi] + kb + quad * 8);
#pragma unroll
            for (int gg = 0; gg < 4; ++gg) bfr[gg] = ldf(brow[gg] + kb + quad * 8);
#pragma unroll
            for (int mi = 0; mi < 4; ++mi)
#pragma unroll
                for (int gg = 0; gg < 4; ++gg)
                    acc[mi][gg] = mfma16(af[mi], bfr[gg], acc[mi][gg]);
        }

#pragma unroll
        for (int mi = 0; mi < 4; ++mi)
#pragma unroll
            for (int r = 0; r < 4; ++r) {
                int m = m0 + mi * 16 + quad * 4 + r;
                int id = idx[m];
                float gv[4];
#pragma unroll
                for (int gg = 0; gg < 4; ++gg) {
                    float wi = (id >= 0) ? wih[(size_t)(gg * 1024 + c) * TT + id] : 0.0f;
                    gv[gg] = acc[mi][gg][r] + bv[gg] + wi;
                }
                size_t off = (size_t)m * HD + c;
                float cn = sigf(gv[1]) * cst[off] + sigf(gv[0]) * tanhf(gv[2]);
                float hn = sigf(gv[3]) * tanhf(cn);
                cst[off] = cn;
                hdec[off] = hn;
                if (t + 1 < LQ)
                    hout[off] = (bf16_t)(hn + (float)encb[((size_t)(t + 1) * NB + m) * HD + c]);
            }
        gsync(bcnt, bgen, 128, g);

        // ================= phase B: logits / softmax / argmax / loss =======
        const float4* hr = (const float4*)(hdec + (size_t)b * HD);
        float a0 = ob0, a1 = ob1;
        for (int k = 0; k < HD / 4; ++k) {
            float4 h4 = hr[k];
            float4 x0 = wl0[k];
            float4 x1 = wl1[k];
            a0 += h4.x * x0.x + h4.y * x0.y + h4.z * x0.z + h4.w * x0.w;
            a1 += h4.x * x1.x + h4.y * x1.y + h4.z * x1.z + h4.w * x1.w;
        }
        float mx = fmaxf(a0, a1);
#pragma unroll
        for (int off2 = 32; off2 > 0; off2 >>= 1) mx = fmaxf(mx, __shfl_xor(mx, off2));
        float sm = __expf(a0 - mx) + __expf(a1 - mx);
#pragma unroll
        for (int off2 = 32; off2 > 0; off2 >>= 1) sm += __shfl_xor(sm, off2);
        float lse = mx + logf(sm);
        size_t pbase = (size_t)b * (LQ * TT) + (size_t)t * TT;
        prob_out[pbase + lane] = __expf(a0 - lse);
        prob_out[pbase + lane + 64] = __expf(a1 - lse);

        // first-max argmax (smaller index wins ties)
        float bvv;
        int bix;
        if (a1 > a0) { bvv = a1; bix = lane + 64; } else { bvv = a0; bix = lane; }
#pragma unroll
        for (int off2 = 32; off2 > 0; off2 >>= 1) {
            float ov = __shfl_xor(bvv, off2);
            int oi = __shfl_xor(bix, off2);
            if (ov > bvv || (ov == bvv && oi < bix)) { bvv = ov; bix = oi; }
        }
        if (lane == 0) idx[b] = bix;

        int tg = tags[b * LQ + t];
        float l0 = __shfl(a0, tg & 63);
        float l1 = __shfl(a1, tg & 63);
        float lv = (tg >= 64) ? l1 : l0;
        if (lane == 0) loss_acc += -(lv - lse) * (1.0f / 128.0f);
        gsync(bcnt, bgen, 128, g);
    }
    if (lane == 0) atomicAdd(loss_out, loss_acc);
}

// ---------------------------------------------------------------------------
extern "C" void kernel_launch(void* const* d_in, const int* in_sizes, int n_in,
                              void* d_out, int out_size, void* d_ws, size_t ws_size,
                              hipStream_t stream) {
    (void)in_sizes; (void)n_in; (void)out_size;
    const int*   ids    = (const int*)d_in[0];
    const int*   tags   = (const int*)d_in[1];
    const float* embed  = (const float*)d_in[2];
    const float* e0_wih = (const float*)d_in[3];
    const float* e0_whh = (const float*)d_in[4];
    const float* e0_b   = (const float*)d_in[5];
    const float* e1_wih = (const float*)d_in[6];
    const float* e1_whh = (const float*)d_in[7];
    const float* e1_b   = (const float*)d_in[8];
    const float* d_wih  = (const float*)d_in[9];
    const float* d_whh  = (const float*)d_in[10];
    const float* d_b    = (const float*)d_in[11];
    const float* out_w  = (const float*)d_in[12];
    const float* out_b  = (const float*)d_in[13];
    float* prob = (float*)d_out;

    char* ws = (char*)d_ws;
    size_t off = 0;
    auto alloc = [&](size_t bytes) -> void* {
        void* p = ws + off;
        off += (bytes + 255) & ~(size_t)255;
        return p;
    };
    // bf16 copies of MFMA-fed tensors (~60 MiB):
    bf16_t* embB   = (bf16_t*)alloc((size_t)30000 * 512 * 2);
    bf16_t* e0wihB = (bf16_t*)alloc((size_t)2 * 2048 * 512 * 2);
    bf16_t* e0whhB = (bf16_t*)alloc((size_t)2 * 2048 * 512 * 2);
    bf16_t* e1wihB = (bf16_t*)alloc((size_t)2 * 2048 * 1024 * 2);
    bf16_t* e1whhB = (bf16_t*)alloc((size_t)2 * 2048 * 512 * 2);
    bf16_t* dwhhB  = (bf16_t*)alloc((size_t)4096 * 1024 * 2);
    // state / activations (~85 MiB):
    bf16_t* h1    = (bf16_t*)alloc((size_t)LQ * NB * 1024 * 2);        // enc0 out
    bf16_t* encb  = (bf16_t*)alloc((size_t)LQ * NB * 1024 * 2);        // enc1 out
    bf16_t* hstE  = (bf16_t*)alloc((size_t)2 * 2 * 2 * NB * 512 * 2);  // [layer][buf][dir][N][HE]
    float*  cstE  = (float*)alloc((size_t)2 * 2 * NB * 512 * 4);       // [layer][dir][N][HE]
    bf16_t* hinD  = (bf16_t*)alloc((size_t)2 * NB * HD * 2);           // [buf]
    float*  cstD  = (float*)alloc((size_t)NB * HD * 4);
    float*  hdec  = (float*)alloc((size_t)NB * HD * 4);
    int*    idx   = (int*)alloc(NB * 4);
    unsigned* bar = (unsigned*)alloc(2 * 4);                           // {cnt, gen}
    size_t fixed_end = off;

    // Step-chunked input-projection gate buffer (CH MiB), sized from ws_size.
    static const int ch_opts[] = {40, 32, 20, 16, 10, 8, 5, 4, 2, 1};
    int CH = 1;
    for (int i = 0; i < 10; ++i) {
        size_t need = (size_t)ch_opts[i] * NB * 4096 * 2;
        if (fixed_end + need <= ws_size) { CH = ch_opts[i]; break; }
    }
    bf16_t* xgc = (bf16_t*)alloc((size_t)CH * NB * 4096 * 2);

    // ---- one-time weight conversion ----
    auto cvt = [&](const float* s, bf16_t* d, size_t n) {
        int n4 = (int)(n / 4);
        k_cvt<<<dim3((n4 + 255) / 256), 256, 0, stream>>>(s, d, n4);
    };
    cvt(embed, embB, (size_t)30000 * 512);
    cvt(e0_wih, e0wihB, (size_t)2 * 2048 * 512);
    cvt(e0_whh, e0whhB, (size_t)2 * 2048 * 512);
    cvt(e1_wih, e1wihB, (size_t)2 * 2048 * 1024);
    cvt(e1_whh, e1whhB, (size_t)2 * 2048 * 512);
    cvt(d_whh, dwhhB, (size_t)4096 * 1024);

    const size_t HS_LAYER = (size_t)2 * 2 * NB * 512;  // hstE per-layer elems
    const size_t CST_LAYER = (size_t)2 * NB * 512;     // cstE per-layer floats

    hipMemsetAsync(hstE, 0, (size_t)2 * HS_LAYER * 2, stream);
    hipMemsetAsync(cstE, 0, (size_t)2 * CST_LAYER * 4, stream);
    hipMemsetAsync(bar, 0, 8, stream);
    hipMemsetAsync(prob + (size_t)NB * LQ * TT, 0, 4, stream);  // loss scalar

    // ---- encoder layer 0 ----
    for (int cc = 0; cc < LQ / CH; ++cc) {
        int s0 = cc * CH;
        k_xg0c<<<dim3(CH * 2, 32, 2), 64, 0, stream>>>(ids, embB, e0wihB, xgc, s0);
        k_enc_chunk<<<dim3(128), 64, 0, stream>>>(hstE, e0whhB, e0_b, xgc, cstE, h1,
                                                  bar, bar + 1, s0, CH);
    }
    // ---- encoder layer 1 ----
    for (int cc = 0; cc < LQ / CH; ++cc) {
        int s0 = cc * CH;
        k_xg1c<<<dim3(CH * 2, 32, 2), 64, 0, stream>>>(h1, e1wihB, xgc, s0);
        k_enc_chunk<<<dim3(128), 64, 0, stream>>>(hstE + HS_LAYER, e1whhB, e1_b, xgc,
                                                  cstE + CST_LAYER, encb,
                                                  bar, bar + 1, s0, CH);
    }
    // ---- decoder (one persistent launch) ----
    k_dec_persist<<<dim3(128), 64, 0, stream>>>(encb, dwhhB, d_b, d_wih, out_w, out_b,
                                                tags, hinD, cstD, hdec, idx,
                                                bar, bar + 1, prob,
                                                prob + (size_t)NB * LQ * TT);
}

// Round 3
// 20153.743 us; speedup vs baseline: 1.3977x; 1.3977x over previous
//
#include <hip/hip_runtime.h>

// ---------------------------------------------------------------------------
// FocusModel: embed -> bidir LSTM (E=512->HE=512) -> bidir LSTM (1024->512)
//          -> decoder LSTM (HD=1024, one-hot argmax feedback) -> softmax/loss
// R6: R5's persistent kernels worked but the acq/rel+threadfence barrier
// lowered to buffer_inv/buffer_wbl2 each step, evicting the L2-resident
// weights (FETCH 570 MB, 50 GB/s, 100 us/step in the decoder). This round
// removes ALL fences:
//   - h-state is written to per-timestep RING slots (never-reused addresses
//     within a launch), so plain cached loads cannot observe stale lines.
//   - barrier arrival uses RELEASE fetch_add (vmcnt drain + wbl2 of dirty
//     lines only -> weights stay cached); waiters spin on RELAXED agent
//     loads. No acquire anywhere -> no buffer_inv -> no cache nuking.
//   - same-address state (idx, hdec row) is read via relaxed agent-scope
//     atomic loads (coherent-point reads, few dozen per step).
//   - LSTM cell state lives in registers (block ownership is constant).
// Math identical to the verified R3/R5 per-step kernels; logits stay f32.
// ---------------------------------------------------------------------------

typedef __bf16 bf16_t;
typedef __bf16 bf16x8 __attribute__((ext_vector_type(8)));
typedef __bf16 bf16x4 __attribute__((ext_vector_type(4)));
typedef float  f32x4  __attribute__((ext_vector_type(4)));

#define NB 128
#define LQ 160
#define EE 512
#define HE 512
#define HD 1024
#define TT 128

__device__ __forceinline__ f32x4 mfma16(bf16x8 a, bf16x8 b, f32x4 c) {
    return __builtin_amdgcn_mfma_f32_16x16x32_bf16(a, b, c, 0, 0, 0);
}
__device__ __forceinline__ bf16x8 ldf(const bf16_t* p) { return *(const bf16x8*)p; }
__device__ __forceinline__ float sigf(float x) { return 1.0f / (1.0f + __expf(-x)); }

// 8 f32 -> bf16x8 (RNE, same numerics as k_cvt).
__device__ __forceinline__ bf16x8 cvt8(const float* p) {
    float4 f0 = ((const float4*)p)[0];
    float4 f1 = ((const float4*)p)[1];
    bf16x8 a;
    a[0] = (bf16_t)f0.x; a[1] = (bf16_t)f0.y; a[2] = (bf16_t)f0.z; a[3] = (bf16_t)f0.w;
    a[4] = (bf16_t)f1.x; a[5] = (bf16_t)f1.y; a[6] = (bf16_t)f1.z; a[7] = (bf16_t)f1.w;
    return a;
}

// Device-scope grid barrier, fence-free. Arrival: RELEASE fetch_add (drains
// vmcnt + writes back dirty L2 lines -> producers' stores reach the coherent
// point). Waiters: RELAXED agent spin (coherent-point load, no cache inval).
// Readers see fresh data because state addresses are ring-fresh (cold lines)
// or read via agent-scope atomic loads.
__device__ __forceinline__ void gsync(unsigned* cnt, unsigned* gen,
                                      unsigned nblk, unsigned& g) {
    __syncthreads();
    if (threadIdx.x == 0) {
        unsigned old = __hip_atomic_fetch_add(cnt, 1u, __ATOMIC_RELEASE,
                                              __HIP_MEMORY_SCOPE_AGENT);
        if (old == nblk - 1u) {
            __hip_atomic_store(cnt, 0u, __ATOMIC_RELAXED, __HIP_MEMORY_SCOPE_AGENT);
            __hip_atomic_fetch_add(gen, 1u, __ATOMIC_RELEASE,
                                   __HIP_MEMORY_SCOPE_AGENT);
        } else {
            while (__hip_atomic_load(gen, __ATOMIC_RELAXED,
                                     __HIP_MEMORY_SCOPE_AGENT) <= g) {
                __builtin_amdgcn_s_sleep(2);
            }
        }
    }
    __syncthreads();
    g += 1;
}

// f32 -> bf16 bulk convert (n4 = n/4, all sizes divisible by 4).
__global__ __launch_bounds__(256) void k_cvt(const float* __restrict__ src,
                                             bf16_t* __restrict__ dst, int n4) {
    int i = blockIdx.x * 256 + threadIdx.x;
    if (i < n4) {
        float4 v = ((const float4*)src)[i];
        bf16x4 o;
        o[0] = (bf16_t)v.x; o[1] = (bf16_t)v.y; o[2] = (bf16_t)v.z; o[3] = (bf16_t)v.w;
        ((bf16x4*)dst)[i] = o;
    }
}

// ---------------------------------------------------------------------------
// Chunked input projection, layer 0. Rows m = (s-s0)*128 + b; per-direction
// source timestep t = d ? L-1-s : s; A-row = embed[ids[b][t]] (f32 gather,
// converted in-register). grid (CH*2, 32, 2), block 64.
// ---------------------------------------------------------------------------
__global__ __launch_bounds__(64) void k_xg0c(const int* __restrict__ ids,
                                             const float* __restrict__ embed,
                                             const bf16_t* __restrict__ wih,
                                             bf16_t* __restrict__ xgc,
                                             int s0) {
    const int lane = threadIdx.x;
    const int l15 = lane & 15, quad = lane >> 4;
    const int m0 = blockIdx.x * 64;
    const int n0 = blockIdx.y * 64;
    const int d  = blockIdx.z;
    const bf16_t* Wd = wih + (size_t)d * 2048 * 512;

    const float* arow[4];
#pragma unroll
    for (int mi = 0; mi < 4; ++mi) {
        int m = m0 + mi * 16 + l15;
        int b = m & 127, s = s0 + (m >> 7);
        int t = d ? (LQ - 1 - s) : s;
        int id = ids[b * LQ + t];
        arow[mi] = embed + (size_t)id * EE;
    }
    const bf16_t* brow[4];
#pragma unroll
    for (int ni = 0; ni < 4; ++ni) brow[ni] = Wd + (size_t)(n0 + ni * 16 + l15) * 512;

    f32x4 acc[4][4] = {};
    for (int kb = 0; kb < 512; kb += 32) {
        bf16x8 af[4], bfr[4];
#pragma unroll
        for (int mi = 0; mi < 4; ++mi) af[mi] = cvt8(arow[mi] + kb + quad * 8);
#pragma unroll
        for (int ni = 0; ni < 4; ++ni) bfr[ni] = ldf(brow[ni] + kb + quad * 8);
#pragma unroll
        for (int mi = 0; mi < 4; ++mi)
#pragma unroll
            for (int ni = 0; ni < 4; ++ni)
                acc[mi][ni] = mfma16(af[mi], bfr[ni], acc[mi][ni]);
    }
#pragma unroll
    for (int mi = 0; mi < 4; ++mi)
#pragma unroll
        for (int ni = 0; ni < 4; ++ni)
#pragma unroll
            for (int r = 0; r < 4; ++r) {
                int m = m0 + mi * 16 + quad * 4 + r;
                int n = n0 + ni * 16 + l15;
                xgc[(size_t)m * 4096 + d * 2048 + n] = (bf16_t)acc[mi][ni][r];
            }
}

// Chunked input projection, layer 1: A-row = h1ring[1+t][b] (1024 wide), K=1024.
__global__ __launch_bounds__(64) void k_xg1c(const bf16_t* __restrict__ h1,
                                             const bf16_t* __restrict__ wih,
                                             bf16_t* __restrict__ xgc,
                                             int s0) {
    const int lane = threadIdx.x;
    const int l15 = lane & 15, quad = lane >> 4;
    const int m0 = blockIdx.x * 64;
    const int n0 = blockIdx.y * 64;
    const int d  = blockIdx.z;
    const bf16_t* Wd = wih + (size_t)d * 2048 * 1024;

    const bf16_t* arow[4];
#pragma unroll
    for (int mi = 0; mi < 4; ++mi) {
        int m = m0 + mi * 16 + l15;
        int b = m & 127, s = s0 + (m >> 7);
        int t = d ? (LQ - 1 - s) : s;
        arow[mi] = h1 + ((size_t)(1 + t) * NB + b) * 1024;
    }
    const bf16_t* brow[4];
#pragma unroll
    for (int ni = 0; ni < 4; ++ni) brow[ni] = Wd + (size_t)(n0 + ni * 16 + l15) * 1024;

    f32x4 acc[4][4] = {};
    for (int kb = 0; kb < 1024; kb += 32) {
        bf16x8 af[4], bfr[4];
#pragma unroll
        for (int mi = 0; mi < 4; ++mi) af[mi] = ldf(arow[mi] + kb + quad * 8);
#pragma unroll
        for (int ni = 0; ni < 4; ++ni) bfr[ni] = ldf(brow[ni] + kb + quad * 8);
#pragma unroll
        for (int mi = 0; mi < 4; ++mi)
#pragma unroll
            for (int ni = 0; ni < 4; ++ni)
                acc[mi][ni] = mfma16(af[mi], bfr[ni], acc[mi][ni]);
    }
#pragma unroll
    for (int mi = 0; mi < 4; ++mi)
#pragma unroll
        for (int ni = 0; ni < 4; ++ni)
#pragma unroll
            for (int r = 0; r < 4; ++r) {
                int m = m0 + mi * 16 + quad * 4 + r;
                int n = n0 + ni * 16 + l15;
                xgc[(size_t)m * 4096 + d * 2048 + n] = (bf16_t)acc[mi][ni][r];
            }
}

// ---------------------------------------------------------------------------
// Persistent encoder chunk. 128 blocks x 64 thr; block bi -> m-block (bi&1),
// col-block ((bi>>1)&31), dir (bi>>6). Recurrent h read/written directly in
// the per-timestep ring hring[1+t][b][d*512+c] (slot 0 and LQ+1 are zeros).
// Cell state in registers across the chunk; persisted to cst between chunks.
// ---------------------------------------------------------------------------
__global__ __launch_bounds__(64) void k_enc_chunk(bf16_t* __restrict__ hring,
                                                  const bf16_t* __restrict__ whh,
                                                  const float* __restrict__ bias,
                                                  const bf16_t* __restrict__ xgc,
                                                  float* __restrict__ cst,
                                                  unsigned* __restrict__ bcnt,
                                                  unsigned* __restrict__ bgen,
                                                  int s0, int nsteps) {
    unsigned g = __hip_atomic_load(bgen, __ATOMIC_RELAXED, __HIP_MEMORY_SCOPE_AGENT);
    const int lane = threadIdx.x;
    const int l15 = lane & 15, quad = lane >> 4;
    const int bi = blockIdx.x;
    const int m0 = (bi & 1) * 64;
    const int c0 = ((bi >> 1) & 31) * 16;
    const int d  = bi >> 6;

    const bf16_t* Wd = whh + (size_t)d * 2048 * 512;
    const bf16_t* brow[4];
#pragma unroll
    for (int g4 = 0; g4 < 4; ++g4) brow[g4] = Wd + (size_t)(g4 * 512 + c0 + l15) * 512;
    const int c = c0 + l15;
    float bv[4];
#pragma unroll
    for (int g4 = 0; g4 < 4; ++g4) bv[g4] = bias[d * 2048 + g4 * 512 + c];
    size_t aoff[4];
#pragma unroll
    for (int mi = 0; mi < 4; ++mi) aoff[mi] = (size_t)(m0 + mi * 16 + l15) * 1024;

    // cell state in registers (block ownership constant across steps)
    float creg[4][4];
#pragma unroll
    for (int mi = 0; mi < 4; ++mi)
#pragma unroll
        for (int r = 0; r < 4; ++r) {
            int m = m0 + mi * 16 + quad * 4 + r;
            creg[mi][r] = cst[((size_t)d * NB + m) * 512 + c];
        }

    for (int s = s0; s < s0 + nsteps; ++s) {
        const int t     = d ? (LQ - 1 - s) : s;
        const int tprev = d ? (LQ - s)     : (s - 1);
        const bf16_t* abase = hring + ((size_t)(1 + tprev) * NB) * 1024 + (size_t)d * 512;

        f32x4 acc[4][4] = {};  // [mi][gate]
        for (int kb = 0; kb < 512; kb += 32) {
            bf16x8 af[4], bfr[4];
#pragma unroll
            for (int mi = 0; mi < 4; ++mi) af[mi] = ldf(abase + aoff[mi] + kb + quad * 8);
#pragma unroll
            for (int g4 = 0; g4 < 4; ++g4) bfr[g4] = ldf(brow[g4] + kb + quad * 8);
#pragma unroll
            for (int mi = 0; mi < 4; ++mi)
#pragma unroll
                for (int g4 = 0; g4 < 4; ++g4)
                    acc[mi][g4] = mfma16(af[mi], bfr[g4], acc[mi][g4]);
        }

        bf16_t* wbase = hring + ((size_t)(1 + t) * NB) * 1024 + (size_t)d * 512;
#pragma unroll
        for (int mi = 0; mi < 4; ++mi)
#pragma unroll
            for (int r = 0; r < 4; ++r) {
                int m = m0 + mi * 16 + quad * 4 + r;
                size_t xoff = ((size_t)(s - s0) * NB + m) * 4096 + (size_t)d * 2048;
                float gi = acc[mi][0][r] + (float)xgc[xoff + 0 * 512 + c] + bv[0];
                float gf = acc[mi][1][r] + (float)xgc[xoff + 1 * 512 + c] + bv[1];
                float gg = acc[mi][2][r] + (float)xgc[xoff + 2 * 512 + c] + bv[2];
                float go = acc[mi][3][r] + (float)xgc[xoff + 3 * 512 + c] + bv[3];
                float cn = sigf(gf) * creg[mi][r] + sigf(gi) * tanhf(gg);
                float hn = sigf(go) * tanhf(cn);
                creg[mi][r] = cn;
                wbase[(size_t)m * 1024 + c] = (bf16_t)hn;
            }
        if (s + 1 < s0 + nsteps) gsync(bcnt, bgen, 128, g);
    }

#pragma unroll
    for (int mi = 0; mi < 4; ++mi)
#pragma unroll
        for (int r = 0; r < 4; ++r) {
            int m = m0 + mi * 16 + quad * 4 + r;
            cst[((size_t)d * NB + m) * 512 + c] = creg[mi][r];
        }
}

// ---------------------------------------------------------------------------
// Persistent decoder: init + 160 steps, 128 blocks x 64 thr.
// Phase A: gate GEMM (h from ring hseq[t], writes hseq[t+1] = h + enc[t+1])
//   + cell math (cell state in regs), hdec (f32) for logits. -> gsync
// Phase B: block bi = batch b; lane n computes tags n and n+64; hdec row
//   staged to LDS via agent-scope atomic loads; shuffle softmax / argmax /
//   loss. idx[b] feeds next step's phase A (agent-scope atomic loads). -> gsync
// ---------------------------------------------------------------------------
__global__ __launch_bounds__(64) void k_dec_persist(const bf16_t* __restrict__ encb,
                                                    const bf16_t* __restrict__ whh,
                                                    const float* __restrict__ bias,
                                                    const float* __restrict__ wih,
                                                    const float* __restrict__ out_w,
                                                    const float* __restrict__ out_b,
                                                    const int* __restrict__ tags,
                                                    bf16_t* __restrict__ hseq,
                                                    float* __restrict__ hdec,
                                                    int* __restrict__ idx,
                                                    unsigned* __restrict__ bcnt,
                                                    unsigned* __restrict__ bgen,
                                                    float* __restrict__ prob_out,
                                                    float* __restrict__ loss_out) {
    unsigned g = __hip_atomic_load(bgen, __ATOMIC_RELAXED, __HIP_MEMORY_SCOPE_AGENT);
    const int lane = threadIdx.x;
    const int bi = blockIdx.x;
    const int l15 = lane & 15, quad = lane >> 4;
    const int m0 = (bi & 1) * 64;
    const int c0 = (bi >> 1) * 16;
    const int c = c0 + l15;

    // ---- init own cells: hseq[0] = enc[0] (ring slot 1), c0 = [fb, fb] ----
    float creg[4][4];
#pragma unroll
    for (int mi = 0; mi < 4; ++mi)
#pragma unroll
        for (int r = 0; r < 4; ++r) {
            int m = m0 + mi * 16 + quad * 4 + r;
            creg[mi][r] = (float)encb[((size_t)1 * NB + m) * 1024 + 512 + (c & 511)];
            hseq[(size_t)m * HD + c] = encb[((size_t)1 * NB + m) * 1024 + c];
        }
    if (bi < 2) idx[bi * 64 + lane] = -1;

    // ---- hoisted gate-phase constants ----
    const bf16_t* brow[4];
#pragma unroll
    for (int g4 = 0; g4 < 4; ++g4) brow[g4] = whh + (size_t)(g4 * 1024 + c0 + l15) * 1024;
    float bv[4];
#pragma unroll
    for (int g4 = 0; g4 < 4; ++g4) bv[g4] = bias[g4 * 1024 + c];
    size_t aoff[4];
#pragma unroll
    for (int mi = 0; mi < 4; ++mi) aoff[mi] = (size_t)(m0 + mi * 16 + l15) * 1024;

    // ---- hoisted logits constants (block bi = batch) ----
    const int b = bi;
    const float4* wl0 = (const float4*)(out_w + (size_t)lane * HD);
    const float4* wl1 = (const float4*)(out_w + (size_t)(lane + 64) * HD);
    const float ob0 = out_b[lane], ob1 = out_b[lane + 64];
    float loss_acc = 0.0f;
    __shared__ float hrow[HD];

    gsync(bcnt, bgen, 128, g);

    for (int t = 0; t < LQ; ++t) {
        // ================= phase A: gates + cell =================
        const bf16_t* hin = hseq + (size_t)t * (NB * HD);

        // hoist idx reads (coherent-point loads, hidden under the GEMM)
        int idr[4][4];
#pragma unroll
        for (int mi = 0; mi < 4; ++mi)
#pragma unroll
            for (int r = 0; r < 4; ++r) {
                int m = m0 + mi * 16 + quad * 4 + r;
                idr[mi][r] = __hip_atomic_load(idx + m, __ATOMIC_RELAXED,
                                               __HIP_MEMORY_SCOPE_AGENT);
            }

        f32x4 acc[4][4] = {};
        for (int kb = 0; kb < 1024; kb += 32) {
            bf16x8 af[4], bfr[4];
#pragma unroll
            for (int mi = 0; mi < 4; ++mi) af[mi] = ldf(hin + aoff[mi] + kb + quad * 8);
#pragma unroll
            for (int g4 = 0; g4 < 4; ++g4) bfr[g4] = ldf(brow[g4] + kb + quad * 8);
#pragma unroll
            for (int mi = 0; mi < 4; ++mi)
#pragma unroll
                for (int g4 = 0; g4 < 4; ++g4)
                    acc[mi][g4] = mfma16(af[mi], bfr[g4], acc[mi][g4]);
        }

        bf16_t* wnext = hseq + (size_t)(t + 1) * (NB * HD);
#pragma unroll
        for (int mi = 0; mi < 4; ++mi)
#pragma unroll
            for (int r = 0; r < 4; ++r) {
                int m = m0 + mi * 16 + quad * 4 + r;
                int id = idr[mi][r];
                float gv[4];
#pragma unroll
                for (int g4 = 0; g4 < 4; ++g4) {
                    float wi = (id >= 0) ? wih[(size_t)(g4 * 1024 + c) * TT + id] : 0.0f;
                    gv[g4] = acc[mi][g4][r] + bv[g4] + wi;
                }
                float cn = sigf(gv[1]) * creg[mi][r] + sigf(gv[0]) * tanhf(gv[2]);
                float hn = sigf(gv[3]) * tanhf(cn);
                creg[mi][r] = cn;
                hdec[(size_t)m * HD + c] = hn;
                if (t + 1 < LQ)
                    wnext[(size_t)m * HD + c] =
                        (bf16_t)(hn + (float)encb[((size_t)(t + 2) * NB + m) * 1024 + c]);
            }
        gsync(bcnt, bgen, 128, g);

        // ================= phase B: logits / softmax / argmax / loss =======
        // stage hdec row b (written by other blocks) via coherent-point loads
        const unsigned long long* hsrc =
            (const unsigned long long*)(hdec + (size_t)b * HD);
#pragma unroll
        for (int k = 0; k < 8; ++k) {
            unsigned long long v = __hip_atomic_load(
                (unsigned long long*)(hsrc + (size_t)lane * 8 + k),
                __ATOMIC_RELAXED, __HIP_MEMORY_SCOPE_AGENT);
            ((unsigned long long*)hrow)[lane * 8 + k] = v;
        }
        __syncthreads();

        float a0 = ob0, a1 = ob1;
        for (int k = 0; k < HD / 4; ++k) {
            float4 h4 = ((const float4*)hrow)[k];
            float4 x0 = wl0[k];
            float4 x1 = wl1[k];
            a0 += h4.x * x0.x + h4.y * x0.y + h4.z * x0.z + h4.w * x0.w;
            a1 += h4.x * x1.x + h4.y * x1.y + h4.z * x1.z + h4.w * x1.w;
        }
        float mx = fmaxf(a0, a1);
#pragma unroll
        for (int off2 = 32; off2 > 0; off2 >>= 1) mx = fmaxf(mx, __shfl_xor(mx, off2));
        float sm = __expf(a0 - mx) + __expf(a1 - mx);
#pragma unroll
        for (int off2 = 32; off2 > 0; off2 >>= 1) sm += __shfl_xor(sm, off2);
        float lse = mx + logf(sm);
        size_t pbase = (size_t)b * (LQ * TT) + (size_t)t * TT;
        prob_out[pbase + lane] = __expf(a0 - lse);
        prob_out[pbase + lane + 64] = __expf(a1 - lse);

        // first-max argmax (smaller index wins ties)
        float bvv;
        int bix;
        if (a1 > a0) { bvv = a1; bix = lane + 64; } else { bvv = a0; bix = lane; }
#pragma unroll
        for (int off2 = 32; off2 > 0; off2 >>= 1) {
            float ov = __shfl_xor(bvv, off2);
            int oi = __shfl_xor(bix, off2);
            if (ov > bvv || (ov == bvv && oi < bix)) { bvv = ov; bix = oi; }
        }
        if (lane == 0) idx[b] = bix;

        int tg = tags[b * LQ + t];
        float l0 = __shfl(a0, tg & 63);
        float l1 = __shfl(a1, tg & 63);
        float lv = (tg >= 64) ? l1 : l0;
        if (lane == 0) loss_acc += -(lv - lse) * (1.0f / 128.0f);
        gsync(bcnt, bgen, 128, g);
    }
    if (lane == 0) atomicAdd(loss_out, loss_acc);
}

// ---------------------------------------------------------------------------
extern "C" void kernel_launch(void* const* d_in, const int* in_sizes, int n_in,
                              void* d_out, int out_size, void* d_ws, size_t ws_size,
                              hipStream_t stream) {
    (void)in_sizes; (void)n_in; (void)out_size;
    const int*   ids    = (const int*)d_in[0];
    const int*   tags   = (const int*)d_in[1];
    const float* embed  = (const float*)d_in[2];
    const float* e0_wih = (const float*)d_in[3];
    const float* e0_whh = (const float*)d_in[4];
    const float* e0_b   = (const float*)d_in[5];
    const float* e1_wih = (const float*)d_in[6];
    const float* e1_whh = (const float*)d_in[7];
    const float* e1_b   = (const float*)d_in[8];
    const float* d_wih  = (const float*)d_in[9];
    const float* d_whh  = (const float*)d_in[10];
    const float* d_b    = (const float*)d_in[11];
    const float* out_w  = (const float*)d_in[12];
    const float* out_b  = (const float*)d_in[13];
    float* prob = (float*)d_out;

    char* ws = (char*)d_ws;
    size_t off = 0;
    auto alloc = [&](size_t bytes) -> void* {
        void* p = ws + off;
        off += (bytes + 255) & ~(size_t)255;
        return p;
    };
    // bf16 weights (~28 MiB; embed stays f32, converted in-register in xg0):
    bf16_t* e0wihB = (bf16_t*)alloc((size_t)2 * 2048 * 512 * 2);
    bf16_t* e0whhB = (bf16_t*)alloc((size_t)2 * 2048 * 512 * 2);
    bf16_t* e1wihB = (bf16_t*)alloc((size_t)2 * 2048 * 1024 * 2);
    bf16_t* e1whhB = (bf16_t*)alloc((size_t)2 * 2048 * 512 * 2);
    bf16_t* dwhhB  = (bf16_t*)alloc((size_t)4096 * 1024 * 2);
    // per-timestep state rings (~121 MiB):
    bf16_t* h1    = (bf16_t*)alloc((size_t)(LQ + 2) * NB * 1024 * 2);  // enc0 ring
    bf16_t* encb  = (bf16_t*)alloc((size_t)(LQ + 2) * NB * 1024 * 2);  // enc1 ring
    bf16_t* hseqD = (bf16_t*)alloc((size_t)LQ * NB * HD * 2);          // decoder ring
    float*  cstE  = (float*)alloc((size_t)2 * 2 * NB * 512 * 4);       // [layer][dir][N][HE]
    float*  hdec  = (float*)alloc((size_t)NB * HD * 4);
    int*    idx   = (int*)alloc(NB * 4);
    unsigned* bar = (unsigned*)alloc(256);  // bar[0]=cnt, bar[32]=gen (separate lines)
    size_t fixed_end = off;

    // Step-chunked input-projection gate buffer, sized from ws_size.
    static const int ch_opts[] = {40, 32, 20, 16, 10, 8, 5, 4, 2, 1};
    int CH = 1;
    for (int i = 0; i < 10; ++i) {
        size_t need = (size_t)ch_opts[i] * NB * 4096 * 2;
        if (fixed_end + need <= ws_size) { CH = ch_opts[i]; break; }
    }
    bf16_t* xgc = (bf16_t*)alloc((size_t)CH * NB * 4096 * 2);

    // ---- one-time weight conversion ----
    auto cvt = [&](const float* s, bf16_t* d, size_t n) {
        int n4 = (int)(n / 4);
        k_cvt<<<dim3((n4 + 255) / 256), 256, 0, stream>>>(s, d, n4);
    };
    cvt(e0_wih, e0wihB, (size_t)2 * 2048 * 512);
    cvt(e0_whh, e0whhB, (size_t)2 * 2048 * 512);
    cvt(e1_wih, e1wihB, (size_t)2 * 2048 * 1024);
    cvt(e1_whh, e1whhB, (size_t)2 * 2048 * 512);
    cvt(d_whh, dwhhB, (size_t)4096 * 1024);

    const size_t SLOT = (size_t)NB * 1024;  // ring slot elems
    hipMemsetAsync(h1, 0, SLOT * 2, stream);                            // slot 0
    hipMemsetAsync(h1 + (size_t)(LQ + 1) * SLOT, 0, SLOT * 2, stream);  // slot LQ+1
    hipMemsetAsync(encb, 0, SLOT * 2, stream);
    hipMemsetAsync(encb + (size_t)(LQ + 1) * SLOT, 0, SLOT * 2, stream);
    hipMemsetAsync(cstE, 0, (size_t)2 * 2 * NB * 512 * 4, stream);
    hipMemsetAsync(bar, 0, 256, stream);
    hipMemsetAsync(prob + (size_t)NB * LQ * TT, 0, 4, stream);  // loss scalar

    // ---- encoder layer 0 ----
    for (int cc = 0; cc < LQ / CH; ++cc) {
        int s0 = cc * CH;
        k_xg0c<<<dim3(CH * 2, 32, 2), 64, 0, stream>>>(ids, embed, e0wihB, xgc, s0);
        k_enc_chunk<<<dim3(128), 64, 0, stream>>>(h1, e0whhB, e0_b, xgc, cstE,
                                                  bar, bar + 32, s0, CH);
    }
    // ---- encoder layer 1 ----
    for (int cc = 0; cc < LQ / CH; ++cc) {
        int s0 = cc * CH;
        k_xg1c<<<dim3(CH * 2, 32, 2), 64, 0, stream>>>(h1, e1wihB, xgc, s0);
        k_enc_chunk<<<dim3(128), 64, 0, stream>>>(encb, e1whhB, e1_b, xgc,
                                                  cstE + (size_t)2 * NB * 512,
                                                  bar, bar + 32, s0, CH);
    }
    // ---- decoder (one persistent launch) ----
    k_dec_persist<<<dim3(128), 64, 0, stream>>>(encb, dwhhB, d_b, d_wih, out_w, out_b,
                                                tags, hseqD, hdec, idx,
                                                bar, bar + 32, prob,
                                                prob + (size_t)NB * LQ * TT);
}